// Round 1
// baseline (1315.957 us; speedup 1.0000x reference)
//
#include <hip/hip_runtime.h>
#include <math.h>

#define B_    4
#define T_    2048
#define D_    1024
#define DB_   256
#define DKk_  128
#define KV_   48
#define DIN_  1408
#define NT_   (B_ * T_)      // 8192 tokens
#define RAD_  8

// workspace layout (float offsets)
#define OFS_BOUND  0                      // 8192
#define OFS_BSOFT  8192                   // 8192
#define OFS_KEY    16384                  // 8192*48
#define OFS_EK     409600                 // 8192*128
#define OFS_HSTAT  1458176                // 8192*2 (mean_h, rstd_h)
#define OFS_FILMIN 1474560                // 8192*1408
// total = 13,008,896 floats = 52.0 MB

// ---------------------------------------------------------------------------
// K1: boundary logit + key logits (49-col mini-GEMM, 32 tokens / block)
// ---------------------------------------------------------------------------
__global__ __launch_bounds__(256) void k_logits(
    const float* __restrict__ h, const float* __restrict__ bound_w,
    const float* __restrict__ bound_b, const float* __restrict__ key_w,
    const float* __restrict__ key_b, float* __restrict__ ws)
{
    __shared__ float As[32][64];
    __shared__ float Ws[64][64];   // cols 0..47 key, 48 bound, rest unused
    const int tid  = threadIdx.x;
    const int tok0 = blockIdx.x * 32;
    const int c  = tid & 63;       // output column 0..63 (49 used)
    const int rg = tid >> 6;       // 0..3 (wave id)
    float acc[8] = {0,0,0,0,0,0,0,0};

    for (int kc = 0; kc < 1024; kc += 64) {
        #pragma unroll
        for (int i = 0; i < 8; ++i) {
            int row = rg + 4 * i;                    // 0..31
            As[row][c] = h[(size_t)(tok0 + row) * 1024 + kc + c];
        }
        #pragma unroll
        for (int i = 0; i < 12; ++i) {               // 64*48 = 3072 = 256*12
            int l = tid + 256 * i;
            int r = l / 48, cc = l - r * 48;
            Ws[r][cc] = key_w[(size_t)(kc + r) * 48 + cc];
        }
        if (tid < 64) Ws[tid][48] = bound_w[kc + tid];
        __syncthreads();
        #pragma unroll 8
        for (int kk = 0; kk < 64; ++kk) {
            float w = Ws[kk][c];
            #pragma unroll
            for (int i = 0; i < 8; ++i)
                acc[i] += As[rg * 8 + i][kk] * w;
        }
        __syncthreads();
    }

    if (c < 48) {
        float kb = key_b[c];
        #pragma unroll
        for (int i = 0; i < 8; ++i)
            ws[OFS_KEY + (size_t)(tok0 + rg * 8 + i) * 48 + c] = acc[i] + kb;
    } else if (c == 48) {
        float bb = bound_b[0];
        #pragma unroll
        for (int i = 0; i < 8; ++i)
            ws[OFS_BOUND + tok0 + rg * 8 + i] = acc[i] + bb;
    }
}

// ---------------------------------------------------------------------------
// K2: 9-tap conv (zero pad) + sigmoid -> b_soft
// ---------------------------------------------------------------------------
__global__ __launch_bounds__(256) void k_conv(
    const float* __restrict__ conv_w, const float* __restrict__ conv_b,
    float* __restrict__ ws)
{
    int id = blockIdx.x * 256 + threadIdx.x;
    if (id >= NT_) return;
    int b = id >> 11, t = id & 2047;
    float s = conv_b[0];
    #pragma unroll
    for (int i = 0; i < 9; ++i) {
        int tt = t + i - 4;
        if (tt >= 0 && tt < T_) s += ws[OFS_BOUND + b * T_ + tt] * conv_w[i];
    }
    ws[OFS_BSOFT + id] = 1.0f / (1.0f + expf(-s));
}

// ---------------------------------------------------------------------------
// K3: softmax over 48 keys, then p @ key_emb -> ek (128)
// ---------------------------------------------------------------------------
__global__ __launch_bounds__(128) void k_softek(
    const float* __restrict__ key_emb, float* __restrict__ ws)
{
    __shared__ float p[48];
    const int tok = blockIdx.x;
    const int tid = threadIdx.x;
    if (tid < 64) {
        float v = (tid < 48) ? ws[OFS_KEY + (size_t)tok * 48 + tid] : -1e30f;
        float m = v;
        #pragma unroll
        for (int off = 32; off; off >>= 1) m = fmaxf(m, __shfl_xor(m, off, 64));
        float e = (tid < 48) ? expf(v - m) : 0.0f;
        float s = e;
        #pragma unroll
        for (int off = 32; off; off >>= 1) s += __shfl_xor(s, off, 64);
        if (tid < 48) p[tid] = e / s;
    }
    __syncthreads();
    float acc = 0.0f;
    #pragma unroll 8
    for (int k = 0; k < 48; ++k) acc += p[k] * key_emb[k * 128 + tid];
    ws[OFS_EK + (size_t)tok * 128 + tid] = acc;
}

// ---------------------------------------------------------------------------
// K4: build film_in = LN([h, eb, ek]) (store f32); also h-row LN stats
// ---------------------------------------------------------------------------
__global__ __launch_bounds__(256) void k_filmin(
    const float* __restrict__ h, const float* __restrict__ e0,
    const float* __restrict__ e1, const float* __restrict__ ln_in_g,
    const float* __restrict__ ln_in_b, float* __restrict__ ws)
{
    const int tok = blockIdx.x;
    const int tid = threadIdx.x;
    const float bs = ws[OFS_BSOFT + tok];
    float val[6];
    float s_all = 0.f, ss_all = 0.f, s_h = 0.f, ss_h = 0.f;
    int n = 0;
    for (int j = tid; j < DIN_; j += 256, ++n) {
        float v;
        if (j < 1024)       v = h[(size_t)tok * 1024 + j];
        else if (j < 1280)  { int i = j - 1024; v = bs * e1[i] + (1.0f - bs) * e0[i]; }
        else                v = ws[OFS_EK + (size_t)tok * 128 + (j - 1280)];
        val[n] = v;
        s_all += v; ss_all += v * v;
        if (j < 1024) { s_h += v; ss_h += v * v; }
    }
    #pragma unroll
    for (int off = 32; off; off >>= 1) {
        s_all  += __shfl_down(s_all, off);
        ss_all += __shfl_down(ss_all, off);
        s_h    += __shfl_down(s_h, off);
        ss_h   += __shfl_down(ss_h, off);
    }
    __shared__ float red[4][4];
    const int wid = tid >> 6;
    if ((tid & 63) == 0) {
        red[wid][0] = s_all; red[wid][1] = ss_all;
        red[wid][2] = s_h;   red[wid][3] = ss_h;
    }
    __syncthreads();
    float S   = red[0][0] + red[1][0] + red[2][0] + red[3][0];
    float SS  = red[0][1] + red[1][1] + red[2][1] + red[3][1];
    float Sh  = red[0][2] + red[1][2] + red[2][2] + red[3][2];
    float SSh = red[0][3] + red[1][3] + red[2][3] + red[3][3];
    float mean  = S * (1.0f / 1408.0f);
    float var   = SS * (1.0f / 1408.0f) - mean * mean;
    float rstd  = rsqrtf(var + 1e-5f);
    float mean_h = Sh * (1.0f / 1024.0f);
    float var_h  = SSh * (1.0f / 1024.0f) - mean_h * mean_h;
    float rstd_h = rsqrtf(var_h + 1e-5f);
    if (tid == 0) {
        ws[OFS_HSTAT + tok * 2]     = mean_h;
        ws[OFS_HSTAT + tok * 2 + 1] = rstd_h;
    }
    n = 0;
    for (int j = tid; j < DIN_; j += 256, ++n)
        ws[OFS_FILMIN + (size_t)tok * 1408 + j] =
            (val[n] - mean) * rstd * ln_in_g[j] + ln_in_b[j];
}

// ---------------------------------------------------------------------------
// K5: fp32 tiled GEMM (64x64 tokens x cols, dual gamma/beta strips) with
//     fused z = LN(h)*(1+gamma)+beta epilogue writing output slot 0.
// ---------------------------------------------------------------------------
__global__ __launch_bounds__(256) void k_gemm(
    const float* __restrict__ fin, const float* __restrict__ film_w,
    const float* __restrict__ film_b, const float* __restrict__ h,
    const float* __restrict__ hstat, const float* __restrict__ ln_h_g,
    const float* __restrict__ ln_h_b, float* __restrict__ out)
{
    __shared__ __align__(16) float As[16][68];   // [k][m], pad for b128-aligned reads
    __shared__ __align__(16) float Bg[16][64];
    __shared__ __align__(16) float Bb[16][64];
    const int tid = threadIdx.x;
    const int m0 = blockIdx.x * 64;
    const int n0 = blockIdx.y * 64;
    const int tx = tid & 15, ty = tid >> 4;
    const int lr = tid >> 2;            // A-load row 0..63
    const int lc = (tid & 3) * 4;       // A-load k 0,4,8,12
    const int bk = tid >> 4;            // B-load k 0..15
    const int bc = (tid & 15) * 4;      // B-load col
    float ag[4][4] = {}, ab[4][4] = {};

    for (int kc = 0; kc < DIN_; kc += 16) {
        float4 a = *(const float4*)&fin[(size_t)(m0 + lr) * DIN_ + kc + lc];
        As[lc + 0][lr] = a.x; As[lc + 1][lr] = a.y;
        As[lc + 2][lr] = a.z; As[lc + 3][lr] = a.w;
        *(float4*)&Bg[bk][bc] =
            *(const float4*)&film_w[(size_t)(kc + bk) * 2048 + n0 + bc];
        *(float4*)&Bb[bk][bc] =
            *(const float4*)&film_w[(size_t)(kc + bk) * 2048 + 1024 + n0 + bc];
        __syncthreads();
        #pragma unroll
        for (int kk = 0; kk < 16; ++kk) {
            float4 av  = *(const float4*)&As[kk][ty * 4];
            float4 bgv = *(const float4*)&Bg[kk][tx * 4];
            float4 bbv = *(const float4*)&Bb[kk][tx * 4];
            float aa[4]  = {av.x, av.y, av.z, av.w};
            float gg[4]  = {bgv.x, bgv.y, bgv.z, bgv.w};
            float bb2[4] = {bbv.x, bbv.y, bbv.z, bbv.w};
            #pragma unroll
            for (int i = 0; i < 4; ++i)
                #pragma unroll
                for (int j = 0; j < 4; ++j) {
                    ag[i][j] += aa[i] * gg[j];
                    ab[i][j] += aa[i] * bb2[j];
                }
        }
        __syncthreads();
    }

    #pragma unroll
    for (int i = 0; i < 4; ++i) {
        const int tok = m0 + ty * 4 + i;
        const float mh = hstat[tok * 2], rh = hstat[tok * 2 + 1];
        #pragma unroll
        for (int j = 0; j < 4; ++j) {
            const int nc = n0 + tx * 4 + j;
            float g  = ag[i][j] + film_b[nc];
            float bt = ab[i][j] + film_b[1024 + nc];
            float hv = h[(size_t)tok * 1024 + nc];
            float lnh = (hv - mh) * rh * ln_h_g[nc] + ln_h_b[nc];
            out[(size_t)tok * 18 * 1024 + nc] = lnh * (1.0f + g) + bt;
        }
    }
}

// ---------------------------------------------------------------------------
// K6: window copy, slots 1..17 : C[b,t,1+j,:] = h[b, clamp(t+j-8), :]
// ---------------------------------------------------------------------------
__global__ __launch_bounds__(256) void k_window(
    const float* __restrict__ h, float* __restrict__ out)
{
    const int id   = blockIdx.x;
    const int slot = id % 17;
    const int tokg = id / 17;
    const int t = tokg & 2047, b = tokg >> 11;
    int st = t + slot - RAD_;
    st = st < 0 ? 0 : (st > T_ - 1 ? T_ - 1 : st);
    const float4* src = (const float4*)&h[(size_t)(b * T_ + st) * 1024];
    float4* dst = (float4*)&out[((size_t)tokg * 18 + 1 + slot) * 1024];
    dst[threadIdx.x] = src[threadIdx.x];
}

// ---------------------------------------------------------------------------
extern "C" void kernel_launch(void* const* d_in, const int* in_sizes, int n_in,
                              void* d_out, int out_size, void* d_ws, size_t ws_size,
                              hipStream_t stream)
{
    const float* h       = (const float*)d_in[0];
    const float* bound_w = (const float*)d_in[1];
    const float* bound_b = (const float*)d_in[2];
    const float* conv_w  = (const float*)d_in[3];
    const float* conv_b  = (const float*)d_in[4];
    const float* e0      = (const float*)d_in[5];
    const float* e1      = (const float*)d_in[6];
    const float* key_emb = (const float*)d_in[7];
    const float* key_w   = (const float*)d_in[8];
    const float* key_b   = (const float*)d_in[9];
    const float* ln_in_g = (const float*)d_in[10];
    const float* ln_in_b = (const float*)d_in[11];
    const float* film_w  = (const float*)d_in[12];
    const float* film_b  = (const float*)d_in[13];
    const float* ln_h_g  = (const float*)d_in[14];
    const float* ln_h_b  = (const float*)d_in[15];
    float* ws  = (float*)d_ws;
    float* out = (float*)d_out;

    hipLaunchKernelGGL(k_logits, dim3(NT_ / 32), dim3(256), 0, stream,
                       h, bound_w, bound_b, key_w, key_b, ws);
    hipLaunchKernelGGL(k_conv, dim3(NT_ / 256), dim3(256), 0, stream,
                       conv_w, conv_b, ws);
    hipLaunchKernelGGL(k_softek, dim3(NT_), dim3(128), 0, stream, key_emb, ws);
    hipLaunchKernelGGL(k_filmin, dim3(NT_), dim3(256), 0, stream,
                       h, e0, e1, ln_in_g, ln_in_b, ws);
    hipLaunchKernelGGL(k_gemm, dim3(128, 16), dim3(256), 0, stream,
                       ws + OFS_FILMIN, film_w, film_b, h, ws + OFS_HSTAT,
                       ln_h_g, ln_h_b, out);
    hipLaunchKernelGGL(k_window, dim3(NT_ * 17), dim3(256), 0, stream, h, out);
}